// Round 1
// baseline (48.686 us; speedup 1.0000x reference)
//
#include <hip/hip_runtime.h>

// ---------------------------------------------------------------------------
// Problem: out[b, t, k, d] = x[b, 4*(t/4) + FO[t%4][k], PI[t%4][k], d]
//   x:   (B=8, T=32, N=196, D=768) fp32
//   out: (B=8, 32,  K=196, D=768) fp32
// Combined table comb[s][k] = FO[s][k]*196 + PI[s][k], built at compile time
// to exactly mirror the Python _patch_indices / _build_index_tables logic.
// ---------------------------------------------------------------------------

struct Tables { int comb[4][196]; };

constexpr Tables make_tables() {
    Tables t{};
    const int starts[4]  = {45, 48, 87, 90};
    const int psizes[4]  = {3, 5, 7, 9};
    const int offs[4]    = {0, 15, 30, 45};
    for (int srow = 0; srow < 4; ++srow) {
        int pos = 0;
        for (int f = 0; f < 4; ++f) {
            const int ps = psizes[f];
            const int sp = starts[srow] - offs[f];
            const int g  = (ps + 1) / 2;
            int idx[89] = {};          // max 8 + 9*9 = 89 entries
            int n = 0;
            // additional (8 entries)
            idx[n++] = sp;
            idx[n++] = sp + g;
            idx[n++] = sp + 2 * g;
            idx[n++] = sp + 14 * g;
            idx[n++] = sp + 14 * g + 2 * g;
            idx[n++] = sp + 28 * g;
            idx[n++] = sp + 28 * g + g;
            idx[n++] = sp + 28 * g + 2 * g;
            // center (ps*ps entries): 14*i + sp + j + 1 for j in [0,ps) for i in [0,ps)
            for (int j = 0; j < ps; ++j)
                for (int i = 0; i < ps; ++i)
                    idx[n++] = 14 * i + sp + j + 1;
            // insertion sort (duplicates retained, like Python sorted())
            for (int a = 1; a < n; ++a) {
                int v = idx[a];
                int b = a - 1;
                while (b >= 0 && idx[b] > v) { idx[b + 1] = idx[b]; --b; }
                idx[b + 1] = v;
            }
            for (int a = 0; a < n; ++a)
                t.comb[srow][pos++] = f * 196 + idx[a];
        }
    }
    return t;
}

__constant__ Tables c_tab = make_tables();

// D = 768 floats = 192 float4 per row. Rows: B*T*K = 8*32*196 = 50176.
// Total float4 elements: 50176 * 192 = 9,633,792.
__global__ void expand_tubevit_kernel(const float4* __restrict__ x,
                                      float4* __restrict__ out,
                                      int total) {
    int i      = blockIdx.x * blockDim.x + threadIdx.x;
    int stride = gridDim.x * blockDim.x;
    for (; i < total; i += stride) {
        const int c  = i % 192;         // float4 column within D
        const int r  = i / 192;         // output row = (b*32 + t)*196 + k
        const int k  = r % 196;
        const int tb = r / 196;         // b*32 + t  (t in [0,32), 32%4==0 -> tb%4 == t%4)
        const int s  = tb & 3;
        // input row: (b*32 + 4*g)*196 + fo*196 + pi = (tb - s)*196 + comb[s][k]
        const int in_r = (tb - s) * 196 + c_tab.comb[s][k];
        out[i] = x[in_r * 192 + c];
    }
}

extern "C" void kernel_launch(void* const* d_in, const int* in_sizes, int n_in,
                              void* d_out, int out_size, void* d_ws, size_t ws_size,
                              hipStream_t stream) {
    const float4* x   = (const float4*)d_in[0];
    float4*       out = (float4*)d_out;

    const int total = out_size / 4;     // float4 count = 9,633,792
    const int block = 256;
    const int grid  = 4096;             // grid-stride, ~9 iters/thread

    expand_tubevit_kernel<<<grid, block, 0, stream>>>(x, out, total);
}